// Round 4
// baseline (327.882 us; speedup 1.0000x reference)
//
#include <hip/hip_runtime.h>
#include <math.h>

#define NG 4096
#define NN 262144
#define D 128
#define M1 64
#define NH 8
#define EPS 1e-6f

typedef __attribute__((ext_vector_type(8))) short short8;
typedef __attribute__((ext_vector_type(4))) float f32x4;

__device__ inline float leaky(float x) { return x > 0.f ? x : 0.01f * x; }

// fp32 -> bf16 round-to-nearest-even
__device__ inline short f2bf(float f) {
  union { float f; unsigned u; } v; v.f = f;
  unsigned r = (v.u + 0x7fffu + ((v.u >> 16) & 1u)) >> 16;
  return (short)r;
}

// ---------------------------------------------------------------------------
// K0: graph offsets via binary search, once
// ---------------------------------------------------------------------------
__global__ void k0_offs(const int* __restrict__ batch, int* __restrict__ offs) {
  int i = blockIdx.x * 256 + threadIdx.x;
  if (i <= NG) {
    int lo = 0, hi = NN;
    while (lo < hi) {
      int mid = (lo + hi) >> 1;
      if (batch[mid] < i) lo = mid + 1; else hi = mid;
    }
    offs[i] = lo;
  }
}

// ---------------------------------------------------------------------------
// K0b: one-time prep — transpose W3[1024,128] -> W3T[128,1024] bf16 and
// W4[128,128] -> W4T[128,128] bf16 via LDS 64x64 tiles. Blocks 0..31: W3,
// blocks 32..35: W4.
// ---------------------------------------------------------------------------
__global__ __launch_bounds__(256) void k0b_prep(
    const float* __restrict__ W3, const float* __restrict__ W4,
    short* __restrict__ W3T, short* __restrict__ W4T) {
  __shared__ float tile[64][65];
  int b = blockIdx.x, t = threadIdx.x;
  const float* src; short* dst; int kt, nt, tkl;  // tkl = transposed row len (K)
  if (b < 32) { src = W3; dst = W3T; kt = b >> 1; nt = b & 1; tkl = 1024; }
  else        { src = W4; dst = W4T; kt = (b - 32) >> 1; nt = (b - 32) & 1; tkl = 128; }

#pragma unroll
  for (int i = 0; i < 4; ++i) {
    int id = t + 256 * i;           // 1024 float4s per tile
    int r = id >> 4, c4 = (id & 15) * 4;
    float4 v = *(const float4*)(src + (size_t)(kt * 64 + r) * D + nt * 64 + c4);
    tile[r][c4 + 0] = v.x; tile[r][c4 + 1] = v.y;
    tile[r][c4 + 2] = v.z; tile[r][c4 + 3] = v.w;
  }
  __syncthreads();
  int n = t >> 2, kb = (t & 3) * 16;
  short8 p0, p1;
#pragma unroll
  for (int j = 0; j < 8; ++j) {
    p0[j] = f2bf(tile[kb + j][n]);
    p1[j] = f2bf(tile[kb + 8 + j][n]);
  }
  short* o = dst + (size_t)(nt * 64 + n) * tkl + kt * 64 + kb;
  *(short8*)o = p0;
  *(short8*)(o + 8) = p1;
}

// ---------------------------------------------------------------------------
// K1 (MFMA bf16, UNCHANGED from round 3 for attribution):
// h = LN64(leaky(feat@W1+b1)); att = exp(h@W2+b2)
// ---------------------------------------------------------------------------
__global__ __launch_bounds__(256) void k1_att(
    const float* __restrict__ feat, const float* __restrict__ W1,
    const float* __restrict__ b1, const float* __restrict__ g1,
    const float* __restrict__ beta1, const float* __restrict__ W2,
    const float* __restrict__ b2, float* __restrict__ att) {
  __shared__ short W1T[M1][D + 8];
  __shared__ short W2T[16][M1 + 8];
  __shared__ short hb[128][72];

  int t = threadIdx.x;
#pragma unroll
  for (int i = 0; i < 8; ++i) {
    int idx4 = t + 256 * i;
    int k = idx4 >> 4;
    int j = (idx4 & 15) * 4;
    float4 wv = *(const float4*)(W1 + k * M1 + j);
    W1T[j + 0][k] = f2bf(wv.x);
    W1T[j + 1][k] = f2bf(wv.y);
    W1T[j + 2][k] = f2bf(wv.z);
    W1T[j + 3][k] = f2bf(wv.w);
  }
#pragma unroll
  for (int i = 0; i < 4; ++i) {
    int e = t * 4 + i;
    int hh = e >> 6, j = e & 63;
    W2T[hh][j] = (hh < NH) ? f2bf(W2[j * NH + hh]) : (short)0;
  }
  __syncthreads();

  int w = t >> 6, l = t & 63;
  int lr = l & 15, lq = l >> 4;
  int nb = blockIdx.x * 128 + w * 32;

  short8 afr[2][4];
#pragma unroll
  for (int mt = 0; mt < 2; ++mt) {
    const float* rp = feat + (size_t)(nb + mt * 16 + lr) * D + lq * 8;
#pragma unroll
    for (int c = 0; c < 4; ++c) {
      float4 x0 = *(const float4*)(rp + c * 32);
      float4 x1 = *(const float4*)(rp + c * 32 + 4);
      short8 a;
      a[0] = f2bf(x0.x); a[1] = f2bf(x0.y); a[2] = f2bf(x0.z); a[3] = f2bf(x0.w);
      a[4] = f2bf(x1.x); a[5] = f2bf(x1.y); a[6] = f2bf(x1.z); a[7] = f2bf(x1.w);
      afr[mt][c] = a;
    }
  }

  f32x4 acc[2][4];
#pragma unroll
  for (int mt = 0; mt < 2; ++mt)
#pragma unroll
    for (int nt = 0; nt < 4; ++nt) acc[mt][nt] = (f32x4){0.f, 0.f, 0.f, 0.f};
#pragma unroll
  for (int c = 0; c < 4; ++c) {
#pragma unroll
    for (int nt = 0; nt < 4; ++nt) {
      short8 bfr = *(const short8*)&W1T[nt * 16 + lr][c * 32 + lq * 8];
      acc[0][nt] = __builtin_amdgcn_mfma_f32_16x16x32_bf16(afr[0][c], bfr, acc[0][nt], 0, 0, 0);
      acc[1][nt] = __builtin_amdgcn_mfma_f32_16x16x32_bf16(afr[1][c], bfr, acc[1][nt], 0, 0, 0);
    }
  }

  float b1v[4], g1v[4], btv[4];
#pragma unroll
  for (int nt = 0; nt < 4; ++nt) {
    b1v[nt] = b1[nt * 16 + lr];
    g1v[nt] = g1[nt * 16 + lr];
    btv[nt] = beta1[nt * 16 + lr];
  }
#pragma unroll
  for (int mt = 0; mt < 2; ++mt) {
#pragma unroll
    for (int r = 0; r < 4; ++r) {
      float x[4], s1 = 0.f, s2 = 0.f;
#pragma unroll
      for (int nt = 0; nt < 4; ++nt) {
        float xv = leaky(acc[mt][nt][r] + b1v[nt]);
        x[nt] = xv;
        s1 += xv;
        s2 = fmaf(xv, xv, s2);
      }
#pragma unroll
      for (int off = 1; off < 16; off <<= 1) {
        s1 += __shfl_xor(s1, off);
        s2 += __shfl_xor(s2, off);
      }
      float mu = s1 * (1.f / M1);
      float var = s2 * (1.f / M1) - mu * mu;
      float inv = rsqrtf(var + EPS);
      int node = w * 32 + mt * 16 + lq * 4 + r;
#pragma unroll
      for (int nt = 0; nt < 4; ++nt)
        hb[node][nt * 16 + lr] = f2bf((x[nt] - mu) * inv * g1v[nt] + btv[nt]);
    }
  }
  __syncthreads();

  f32x4 acc2[2];
  acc2[0] = (f32x4){0.f, 0.f, 0.f, 0.f};
  acc2[1] = (f32x4){0.f, 0.f, 0.f, 0.f};
#pragma unroll
  for (int c2 = 0; c2 < 2; ++c2) {
    short8 bfr2 = *(const short8*)&W2T[lr][c2 * 32 + lq * 8];
#pragma unroll
    for (int mt = 0; mt < 2; ++mt) {
      short8 af2 = *(const short8*)&hb[w * 32 + mt * 16 + lr][c2 * 32 + lq * 8];
      acc2[mt] = __builtin_amdgcn_mfma_f32_16x16x32_bf16(af2, bfr2, acc2[mt], 0, 0, 0);
    }
  }
  if (lr < NH) {
    float b2v = b2[lr];
#pragma unroll
    for (int mt = 0; mt < 2; ++mt)
#pragma unroll
      for (int r = 0; r < 4; ++r) {
        int node = nb + mt * 16 + lq * 4 + r;
        att[(size_t)node * NH + lr] = expf(acc2[mt][r] + b2v);
      }
  }
}

// ---------------------------------------------------------------------------
// K2: wave-per-graph aggregation, NO LDS, no syncthreads.
// 4 graphs/block; per graph: 2 node-stripes (half-waves) x 32 d4-lanes.
// Depth-2 register ring on feat/att; cross-half reduce via shfl_xor(32).
// ---------------------------------------------------------------------------
__global__ __launch_bounds__(256) void k2_agg(
    const float* __restrict__ feat, const int* __restrict__ offs,
    const float* __restrict__ att, float* __restrict__ out_row) {
  int t = threadIdx.x;
  int w = t >> 6, l = t & 63;
  int g = blockIdx.x * 4 + w;
  int d4 = l & 31, sub = l >> 5;
  int lo = offs[g], hi = offs[g + 1];

  float4 acc[NH];
  float sa[NH];
#pragma unroll
  for (int h = 0; h < NH; ++h) {
    acc[h] = make_float4(0.f, 0.f, 0.f, 0.f);
    sa[h] = 0.f;
  }

  const float4* fv = (const float4*)feat;
  const float4* av = (const float4*)att;

  float4 fb[2], a0b[2], a1b[2];
  int n0 = lo + sub;
#pragma unroll
  for (int i = 0; i < 2; ++i) {
    int ni = n0 + i * 2;
    if (ni < hi) {
      fb[i] = fv[(size_t)ni * 32 + d4];
      a0b[i] = av[(size_t)ni * 2];
      a1b[i] = av[(size_t)ni * 2 + 1];
    }
  }
  int it = 0;
  for (int n = n0; n < hi; n += 2, ++it) {
    int slot = it & 1;
    int np = n + 4;
    float4 fn, a0n, a1n;
    bool pf = np < hi;
    if (pf) {                       // prefetch 2 iterations ahead
      fn = fv[(size_t)np * 32 + d4];
      a0n = av[(size_t)np * 2];
      a1n = av[(size_t)np * 2 + 1];
    }
    float4 fc = fb[slot], A0 = a0b[slot], A1 = a1b[slot];
    float ah[NH] = {A0.x, A0.y, A0.z, A0.w, A1.x, A1.y, A1.z, A1.w};
#pragma unroll
    for (int h = 0; h < NH; ++h) {
      acc[h].x = fmaf(ah[h], fc.x, acc[h].x);
      acc[h].y = fmaf(ah[h], fc.y, acc[h].y);
      acc[h].z = fmaf(ah[h], fc.z, acc[h].z);
      acc[h].w = fmaf(ah[h], fc.w, acc[h].w);
      sa[h] += ah[h];
    }
    if (pf) { fb[slot] = fn; a0b[slot] = a0n; a1b[slot] = a1n; }
  }

  // cross-half (lane ^ 32) butterfly reduce
#pragma unroll
  for (int h = 0; h < NH; ++h) {
    acc[h].x += __shfl_xor(acc[h].x, 32);
    acc[h].y += __shfl_xor(acc[h].y, 32);
    acc[h].z += __shfl_xor(acc[h].z, 32);
    acc[h].w += __shfl_xor(acc[h].w, 32);
    sa[h] += __shfl_xor(sa[h], 32);
  }

  if (sub == 0) {
    float4* orow = (float4*)(out_row + (size_t)g * (NH * D));
#pragma unroll
    for (int h = 0; h < NH; ++h) {
      float inv = (hi > lo) ? 1.f / sa[h] : 0.f;
      float4 v;
      v.x = acc[h].x * inv; v.y = acc[h].y * inv;
      v.z = acc[h].z * inv; v.w = acc[h].w * inv;
      orow[h * 32 + d4] = v;
    }
  }
}

// ---------------------------------------------------------------------------
// K3 (MFMA bf16): o = LN(leaky(X@W3+b3)); o = LN(leaky(o@W4+b4))
// 16 graphs/block, 128 thr = 2 waves (wave nw owns cols nw*64..+64).
// B-frags read directly from L2-resident transposed bf16 weights.
// Cross-wave LN via tiny LDS partials; h round-trips LDS as bf16.
// ---------------------------------------------------------------------------
__global__ __launch_bounds__(128) void k3_mlp(
    const float* __restrict__ X, const short* __restrict__ W3T,
    const float* __restrict__ b3, const float* __restrict__ g3,
    const float* __restrict__ beta3, const short* __restrict__ W4T,
    const float* __restrict__ b4, const float* __restrict__ g4,
    const float* __restrict__ beta4, float* __restrict__ out) {
  __shared__ short hbuf[16][136];
  __shared__ float red[2][2][16];   // [nw][{s1,s2}][row]

  int t = threadIdx.x;
  int nw = t >> 6, l = t & 63;
  int lr = l & 15, lq = l >> 4;
  int gb = blockIdx.x * 16;

  // ---- GEMM1: [16 x 1024] @ W3 -> cols nw*64..+64 (4 N-tiles), K=1024
  const float* xrow = X + (size_t)(gb + lr) * (NH * D) + lq * 8;
  f32x4 acc[4];
#pragma unroll
  for (int nt = 0; nt < 4; ++nt) acc[nt] = (f32x4){0.f, 0.f, 0.f, 0.f};

  float4 x0 = *(const float4*)(xrow);
  float4 x1 = *(const float4*)(xrow + 4);
  for (int kc = 0; kc < 32; ++kc) {
    float4 nx0, nx1;
    if (kc < 31) {                  // prefetch next A chunk
      nx0 = *(const float4*)(xrow + (kc + 1) * 32);
      nx1 = *(const float4*)(xrow + (kc + 1) * 32 + 4);
    }
    short8 a;
    a[0] = f2bf(x0.x); a[1] = f2bf(x0.y); a[2] = f2bf(x0.z); a[3] = f2bf(x0.w);
    a[4] = f2bf(x1.x); a[5] = f2bf(x1.y); a[6] = f2bf(x1.z); a[7] = f2bf(x1.w);
#pragma unroll
    for (int nt = 0; nt < 4; ++nt) {
      int ncol = nw * 64 + nt * 16 + lr;
      short8 b = *(const short8*)(W3T + (size_t)ncol * 1024 + kc * 32 + lq * 8);
      acc[nt] = __builtin_amdgcn_mfma_f32_16x16x32_bf16(a, b, acc[nt], 0, 0, 0);
    }
    x0 = nx0; x1 = nx1;
  }

  // ---- bias + leaky + LN1 (cross-wave)
  float xv[4][4], s1[4] = {0.f, 0.f, 0.f, 0.f}, s2[4] = {0.f, 0.f, 0.f, 0.f};
#pragma unroll
  for (int nt = 0; nt < 4; ++nt) {
    float bb = b3[nw * 64 + nt * 16 + lr];
#pragma unroll
    for (int r = 0; r < 4; ++r) {
      float v = leaky(acc[nt][r] + bb);
      xv[nt][r] = v;
      s1[r] += v;
      s2[r] = fmaf(v, v, s2[r]);
    }
  }
#pragma unroll
  for (int off = 1; off < 16; off <<= 1) {
#pragma unroll
    for (int r = 0; r < 4; ++r) {
      s1[r] += __shfl_xor(s1[r], off);
      s2[r] += __shfl_xor(s2[r], off);
    }
  }
  if (lr == 0) {
#pragma unroll
    for (int r = 0; r < 4; ++r) {
      red[nw][0][lq * 4 + r] = s1[r];
      red[nw][1][lq * 4 + r] = s2[r];
    }
  }
  __syncthreads();
#pragma unroll
  for (int nt = 0; nt < 4; ++nt) {
    int col = nw * 64 + nt * 16 + lr;
    float gg = g3[col], bt = beta3[col];
#pragma unroll
    for (int r = 0; r < 4; ++r) {
      int row = lq * 4 + r;
      float S1 = red[0][0][row] + red[1][0][row];
      float S2 = red[0][1][row] + red[1][1][row];
      float mu = S1 * (1.f / D);
      float var = S2 * (1.f / D) - mu * mu;
      float inv = rsqrtf(var + EPS);
      hbuf[row][col] = f2bf((xv[nt][r] - mu) * inv * gg + bt);
    }
  }
  __syncthreads();

  // ---- GEMM2: [16 x 128] @ W4, K=128
  f32x4 acc2[4];
#pragma unroll
  for (int nt = 0; nt < 4; ++nt) acc2[nt] = (f32x4){0.f, 0.f, 0.f, 0.f};
#pragma unroll
  for (int kc = 0; kc < 4; ++kc) {
    short8 a2 = *(const short8*)&hbuf[lr][kc * 32 + lq * 8];
#pragma unroll
    for (int nt = 0; nt < 4; ++nt) {
      int ncol = nw * 64 + nt * 16 + lr;
      short8 b2 = *(const short8*)(W4T + (size_t)ncol * 128 + kc * 32 + lq * 8);
      acc2[nt] = __builtin_amdgcn_mfma_f32_16x16x32_bf16(a2, b2, acc2[nt], 0, 0, 0);
    }
  }

  // ---- bias + leaky + LN2 + store
#pragma unroll
  for (int r = 0; r < 4; ++r) { s1[r] = 0.f; s2[r] = 0.f; }
#pragma unroll
  for (int nt = 0; nt < 4; ++nt) {
    float bb = b4[nw * 64 + nt * 16 + lr];
#pragma unroll
    for (int r = 0; r < 4; ++r) {
      float v = leaky(acc2[nt][r] + bb);
      xv[nt][r] = v;
      s1[r] += v;
      s2[r] = fmaf(v, v, s2[r]);
    }
  }
#pragma unroll
  for (int off = 1; off < 16; off <<= 1) {
#pragma unroll
    for (int r = 0; r < 4; ++r) {
      s1[r] += __shfl_xor(s1[r], off);
      s2[r] += __shfl_xor(s2[r], off);
    }
  }
  __syncthreads();   // red LN1 reads done above; safe to overwrite
  if (lr == 0) {
#pragma unroll
    for (int r = 0; r < 4; ++r) {
      red[nw][0][lq * 4 + r] = s1[r];
      red[nw][1][lq * 4 + r] = s2[r];
    }
  }
  __syncthreads();
#pragma unroll
  for (int nt = 0; nt < 4; ++nt) {
    int col = nw * 64 + nt * 16 + lr;
    float gg = g4[col], bt = beta4[col];
#pragma unroll
    for (int r = 0; r < 4; ++r) {
      int row = lq * 4 + r;
      float S1 = red[0][0][row] + red[1][0][row];
      float S2 = red[0][1][row] + red[1][1][row];
      float mu = S1 * (1.f / D);
      float var = S2 * (1.f / D) - mu * mu;
      float inv = rsqrtf(var + EPS);
      out[(size_t)(gb + row) * D + col] = (xv[nt][r] - mu) * inv * gg + bt;
    }
  }
}

extern "C" void kernel_launch(void* const* d_in, const int* in_sizes, int n_in,
                              void* d_out, int out_size, void* d_ws, size_t ws_size,
                              hipStream_t stream) {
  (void)in_sizes; (void)n_in; (void)out_size; (void)ws_size;
  const float* feat  = (const float*)d_in[0];
  const int*   batch = (const int*)d_in[1];
  const float* W1    = (const float*)d_in[2];
  const float* b1    = (const float*)d_in[3];
  const float* g1    = (const float*)d_in[4];
  const float* beta1 = (const float*)d_in[5];
  const float* W2    = (const float*)d_in[6];
  const float* b2    = (const float*)d_in[7];
  const float* W3    = (const float*)d_in[8];
  const float* b3    = (const float*)d_in[9];
  const float* g3    = (const float*)d_in[10];
  const float* beta3 = (const float*)d_in[11];
  const float* W4    = (const float*)d_in[12];
  const float* b4    = (const float*)d_in[13];
  const float* g4    = (const float*)d_in[14];
  const float* beta4 = (const float*)d_in[15];
  float* out = (float*)d_out;

  char* ws = (char*)d_ws;
  float* att     = (float*)ws;                                  // 8 MB
  float* out_row = (float*)(ws + (size_t)NN * NH * 4);          // 16.8 MB
  char*  p       = ws + (size_t)NN * NH * 4 + (size_t)NG * NH * D * 4;
  int*   offs    = (int*)p;                                     // 16.4 KB
  short* W3T     = (short*)(p + 32768);                         // 256 KB
  short* W4T     = (short*)(p + 32768 + 262144);                // 32 KB

  k0_offs<<<(NG + 256) / 256, 256, 0, stream>>>(batch, offs);
  k0b_prep<<<36, 256, 0, stream>>>(W3, W4, W3T, W4T);
  k1_att<<<NN / 128, 256, 0, stream>>>(feat, W1, b1, g1, beta1, W2, b2, att);
  k2_agg<<<NG / 4, 256, 0, stream>>>(feat, offs, att, out_row);
  k3_mlp<<<NG / 16, 128, 0, stream>>>(out_row, W3T, b3, g3, beta3, W4T, b4, g4,
                                      beta4, out);
}

// Round 5
// 278.009 us; speedup vs baseline: 1.1794x; 1.1794x over previous
//
#include <hip/hip_runtime.h>
#include <math.h>

#define NG 4096
#define NN 262144
#define D 128
#define M1 64
#define NH 8
#define EPS 1e-6f

typedef __attribute__((ext_vector_type(8))) short short8;
typedef __attribute__((ext_vector_type(4))) float f32x4;

__device__ inline float leaky(float x) { return x > 0.f ? x : 0.01f * x; }

// fp32 -> bf16 round-to-nearest-even
__device__ inline short f2bf(float f) {
  union { float f; unsigned u; } v; v.f = f;
  unsigned r = (v.u + 0x7fffu + ((v.u >> 16) & 1u)) >> 16;
  return (short)r;
}

// ---------------------------------------------------------------------------
// K0: graph offsets via binary search, once
// ---------------------------------------------------------------------------
__global__ void k0_offs(const int* __restrict__ batch, int* __restrict__ offs) {
  int i = blockIdx.x * 256 + threadIdx.x;
  if (i <= NG) {
    int lo = 0, hi = NN;
    while (lo < hi) {
      int mid = (lo + hi) >> 1;
      if (batch[mid] < i) lo = mid + 1; else hi = mid;
    }
    offs[i] = lo;
  }
}

// ---------------------------------------------------------------------------
// K0b: one-time prep — transpose W3[1024,128] -> W3T[128,1024] bf16 and
// W4[128,128] -> W4T[128,128] bf16 via LDS 64x64 tiles.
// ---------------------------------------------------------------------------
__global__ __launch_bounds__(256) void k0b_prep(
    const float* __restrict__ W3, const float* __restrict__ W4,
    short* __restrict__ W3T, short* __restrict__ W4T) {
  __shared__ float tile[64][65];
  int b = blockIdx.x, t = threadIdx.x;
  const float* src; short* dst; int kt, nt, tkl;
  if (b < 32) { src = W3; dst = W3T; kt = b >> 1; nt = b & 1; tkl = 1024; }
  else        { src = W4; dst = W4T; kt = (b - 32) >> 1; nt = (b - 32) & 1; tkl = 128; }

#pragma unroll
  for (int i = 0; i < 4; ++i) {
    int id = t + 256 * i;
    int r = id >> 4, c4 = (id & 15) * 4;
    float4 v = *(const float4*)(src + (size_t)(kt * 64 + r) * D + nt * 64 + c4);
    tile[r][c4 + 0] = v.x; tile[r][c4 + 1] = v.y;
    tile[r][c4 + 2] = v.z; tile[r][c4 + 3] = v.w;
  }
  __syncthreads();
  int n = t >> 2, kb = (t & 3) * 16;
  short8 p0, p1;
#pragma unroll
  for (int j = 0; j < 8; ++j) {
    p0[j] = f2bf(tile[kb + j][n]);
    p1[j] = f2bf(tile[kb + 8 + j][n]);
  }
  short* o = dst + (size_t)(nt * 64 + n) * tkl + kt * 64 + kb;
  *(short8*)o = p0;
  *(short8*)(o + 8) = p1;
}

// ---------------------------------------------------------------------------
// K1 (MFMA bf16, UNCHANGED for attribution):
// h = LN64(leaky(feat@W1+b1)); att = exp(h@W2+b2)
// ---------------------------------------------------------------------------
__global__ __launch_bounds__(256) void k1_att(
    const float* __restrict__ feat, const float* __restrict__ W1,
    const float* __restrict__ b1, const float* __restrict__ g1,
    const float* __restrict__ beta1, const float* __restrict__ W2,
    const float* __restrict__ b2, float* __restrict__ att) {
  __shared__ short W1T[M1][D + 8];
  __shared__ short W2T[16][M1 + 8];
  __shared__ short hb[128][72];

  int t = threadIdx.x;
#pragma unroll
  for (int i = 0; i < 8; ++i) {
    int idx4 = t + 256 * i;
    int k = idx4 >> 4;
    int j = (idx4 & 15) * 4;
    float4 wv = *(const float4*)(W1 + k * M1 + j);
    W1T[j + 0][k] = f2bf(wv.x);
    W1T[j + 1][k] = f2bf(wv.y);
    W1T[j + 2][k] = f2bf(wv.z);
    W1T[j + 3][k] = f2bf(wv.w);
  }
#pragma unroll
  for (int i = 0; i < 4; ++i) {
    int e = t * 4 + i;
    int hh = e >> 6, j = e & 63;
    W2T[hh][j] = (hh < NH) ? f2bf(W2[j * NH + hh]) : (short)0;
  }
  __syncthreads();

  int w = t >> 6, l = t & 63;
  int lr = l & 15, lq = l >> 4;
  int nb = blockIdx.x * 128 + w * 32;

  short8 afr[2][4];
#pragma unroll
  for (int mt = 0; mt < 2; ++mt) {
    const float* rp = feat + (size_t)(nb + mt * 16 + lr) * D + lq * 8;
#pragma unroll
    for (int c = 0; c < 4; ++c) {
      float4 x0 = *(const float4*)(rp + c * 32);
      float4 x1 = *(const float4*)(rp + c * 32 + 4);
      short8 a;
      a[0] = f2bf(x0.x); a[1] = f2bf(x0.y); a[2] = f2bf(x0.z); a[3] = f2bf(x0.w);
      a[4] = f2bf(x1.x); a[5] = f2bf(x1.y); a[6] = f2bf(x1.z); a[7] = f2bf(x1.w);
      afr[mt][c] = a;
    }
  }

  f32x4 acc[2][4];
#pragma unroll
  for (int mt = 0; mt < 2; ++mt)
#pragma unroll
    for (int nt = 0; nt < 4; ++nt) acc[mt][nt] = (f32x4){0.f, 0.f, 0.f, 0.f};
#pragma unroll
  for (int c = 0; c < 4; ++c) {
#pragma unroll
    for (int nt = 0; nt < 4; ++nt) {
      short8 bfr = *(const short8*)&W1T[nt * 16 + lr][c * 32 + lq * 8];
      acc[0][nt] = __builtin_amdgcn_mfma_f32_16x16x32_bf16(afr[0][c], bfr, acc[0][nt], 0, 0, 0);
      acc[1][nt] = __builtin_amdgcn_mfma_f32_16x16x32_bf16(afr[1][c], bfr, acc[1][nt], 0, 0, 0);
    }
  }

  float b1v[4], g1v[4], btv[4];
#pragma unroll
  for (int nt = 0; nt < 4; ++nt) {
    b1v[nt] = b1[nt * 16 + lr];
    g1v[nt] = g1[nt * 16 + lr];
    btv[nt] = beta1[nt * 16 + lr];
  }
#pragma unroll
  for (int mt = 0; mt < 2; ++mt) {
#pragma unroll
    for (int r = 0; r < 4; ++r) {
      float x[4], s1 = 0.f, s2 = 0.f;
#pragma unroll
      for (int nt = 0; nt < 4; ++nt) {
        float xv = leaky(acc[mt][nt][r] + b1v[nt]);
        x[nt] = xv;
        s1 += xv;
        s2 = fmaf(xv, xv, s2);
      }
#pragma unroll
      for (int off = 1; off < 16; off <<= 1) {
        s1 += __shfl_xor(s1, off);
        s2 += __shfl_xor(s2, off);
      }
      float mu = s1 * (1.f / M1);
      float var = s2 * (1.f / M1) - mu * mu;
      float inv = rsqrtf(var + EPS);
      int node = w * 32 + mt * 16 + lq * 4 + r;
#pragma unroll
      for (int nt = 0; nt < 4; ++nt)
        hb[node][nt * 16 + lr] = f2bf((x[nt] - mu) * inv * g1v[nt] + btv[nt]);
    }
  }
  __syncthreads();

  f32x4 acc2[2];
  acc2[0] = (f32x4){0.f, 0.f, 0.f, 0.f};
  acc2[1] = (f32x4){0.f, 0.f, 0.f, 0.f};
#pragma unroll
  for (int c2 = 0; c2 < 2; ++c2) {
    short8 bfr2 = *(const short8*)&W2T[lr][c2 * 32 + lq * 8];
#pragma unroll
    for (int mt = 0; mt < 2; ++mt) {
      short8 af2 = *(const short8*)&hb[w * 32 + mt * 16 + lr][c2 * 32 + lq * 8];
      acc2[mt] = __builtin_amdgcn_mfma_f32_16x16x32_bf16(af2, bfr2, acc2[mt], 0, 0, 0);
    }
  }
  if (lr < NH) {
    float b2v = b2[lr];
#pragma unroll
    for (int mt = 0; mt < 2; ++mt)
#pragma unroll
      for (int r = 0; r < 4; ++r) {
        int node = nb + mt * 16 + lq * 4 + r;
        att[(size_t)node * NH + lr] = expf(acc2[mt][r] + b2v);
      }
  }
}

// ---------------------------------------------------------------------------
// K2: wave-per-graph aggregation. NAMED-REGISTER 2-stage pipeline — no
// arrays with runtime subscripts (round-4's ring was demoted to LDS by
// promote-alloca: LDS_Block_Size=16384, 3.1M bank conflicts, 80 us).
// 4 graphs/block; per graph 2 node-stripes (half-waves) x 32 d4-lanes.
// ---------------------------------------------------------------------------
__global__ __launch_bounds__(256) void k2_agg(
    const float* __restrict__ feat, const int* __restrict__ offs,
    const float* __restrict__ att, float* __restrict__ out_row) {
  int t = threadIdx.x;
  int w = t >> 6, l = t & 63;
  int g = blockIdx.x * 4 + w;
  int d4 = l & 31, sub = l >> 5;
  int lo = offs[g], hi = offs[g + 1];

  float4 acc[NH];
  float sa[NH];
#pragma unroll
  for (int h = 0; h < NH; ++h) {
    acc[h] = make_float4(0.f, 0.f, 0.f, 0.f);
    sa[h] = 0.f;
  }

  const float4* fv = (const float4*)feat;
  const float4* av = (const float4*)att;

  auto body = [&](const float4& fc, const float4& A0, const float4& A1) {
    float ah[NH] = {A0.x, A0.y, A0.z, A0.w, A1.x, A1.y, A1.z, A1.w};
#pragma unroll
    for (int h = 0; h < NH; ++h) {
      acc[h].x = fmaf(ah[h], fc.x, acc[h].x);
      acc[h].y = fmaf(ah[h], fc.y, acc[h].y);
      acc[h].z = fmaf(ah[h], fc.z, acc[h].z);
      acc[h].w = fmaf(ah[h], fc.w, acc[h].w);
      sa[h] += ah[h];
    }
  };

  // stage 0 owns nodes n0, n0+4, ... ; stage 1 owns n0+2, n0+6, ...
  int n0 = lo + sub;
  int n1 = n0 + 2;
  float4 f0, a00, a10, f1, a01, a11;
  if (n0 < hi) {
    f0 = fv[(size_t)n0 * 32 + d4];
    a00 = av[(size_t)n0 * 2];
    a10 = av[(size_t)n0 * 2 + 1];
  }
  if (n1 < hi) {
    f1 = fv[(size_t)n1 * 32 + d4];
    a01 = av[(size_t)n1 * 2];
    a11 = av[(size_t)n1 * 2 + 1];
  }

  for (int n = n0; n < hi; n += 4) {
    {  // stage 0: process node n, prefetch n+4
      int np = n + 4;
      float4 fn, a0n, a1n;
      bool pf = np < hi;
      if (pf) {
        fn = fv[(size_t)np * 32 + d4];
        a0n = av[(size_t)np * 2];
        a1n = av[(size_t)np * 2 + 1];
      }
      body(f0, a00, a10);
      if (pf) { f0 = fn; a00 = a0n; a10 = a1n; }
    }
    if (n + 2 < hi) {  // stage 1: process node n+2, prefetch n+6
      int np = n + 6;
      float4 fn, a0n, a1n;
      bool pf = np < hi;
      if (pf) {
        fn = fv[(size_t)np * 32 + d4];
        a0n = av[(size_t)np * 2];
        a1n = av[(size_t)np * 2 + 1];
      }
      body(f1, a01, a11);
      if (pf) { f1 = fn; a01 = a0n; a11 = a1n; }
    }
  }

  // cross-half (lane ^ 32) butterfly reduce
#pragma unroll
  for (int h = 0; h < NH; ++h) {
    acc[h].x += __shfl_xor(acc[h].x, 32);
    acc[h].y += __shfl_xor(acc[h].y, 32);
    acc[h].z += __shfl_xor(acc[h].z, 32);
    acc[h].w += __shfl_xor(acc[h].w, 32);
    sa[h] += __shfl_xor(sa[h], 32);
  }

  if (sub == 0) {
    float4* orow = (float4*)(out_row + (size_t)g * (NH * D));
#pragma unroll
    for (int h = 0; h < NH; ++h) {
      float inv = (hi > lo) ? 1.f / sa[h] : 0.f;
      float4 v;
      v.x = acc[h].x * inv; v.y = acc[h].y * inv;
      v.z = acc[h].z * inv; v.w = acc[h].w * inv;
      orow[h * 32 + d4] = v;
    }
  }
}

// ---------------------------------------------------------------------------
// K3 (MFMA bf16, UNCHANGED for attribution)
// ---------------------------------------------------------------------------
__global__ __launch_bounds__(128) void k3_mlp(
    const float* __restrict__ X, const short* __restrict__ W3T,
    const float* __restrict__ b3, const float* __restrict__ g3,
    const float* __restrict__ beta3, const short* __restrict__ W4T,
    const float* __restrict__ b4, const float* __restrict__ g4,
    const float* __restrict__ beta4, float* __restrict__ out) {
  __shared__ short hbuf[16][136];
  __shared__ float red[2][2][16];

  int t = threadIdx.x;
  int nw = t >> 6, l = t & 63;
  int lr = l & 15, lq = l >> 4;
  int gb = blockIdx.x * 16;

  const float* xrow = X + (size_t)(gb + lr) * (NH * D) + lq * 8;
  f32x4 acc[4];
#pragma unroll
  for (int nt = 0; nt < 4; ++nt) acc[nt] = (f32x4){0.f, 0.f, 0.f, 0.f};

  float4 x0 = *(const float4*)(xrow);
  float4 x1 = *(const float4*)(xrow + 4);
  for (int kc = 0; kc < 32; ++kc) {
    float4 nx0, nx1;
    if (kc < 31) {
      nx0 = *(const float4*)(xrow + (kc + 1) * 32);
      nx1 = *(const float4*)(xrow + (kc + 1) * 32 + 4);
    }
    short8 a;
    a[0] = f2bf(x0.x); a[1] = f2bf(x0.y); a[2] = f2bf(x0.z); a[3] = f2bf(x0.w);
    a[4] = f2bf(x1.x); a[5] = f2bf(x1.y); a[6] = f2bf(x1.z); a[7] = f2bf(x1.w);
#pragma unroll
    for (int nt = 0; nt < 4; ++nt) {
      int ncol = nw * 64 + nt * 16 + lr;
      short8 b = *(const short8*)(W3T + (size_t)ncol * 1024 + kc * 32 + lq * 8);
      acc[nt] = __builtin_amdgcn_mfma_f32_16x16x32_bf16(a, b, acc[nt], 0, 0, 0);
    }
    x0 = nx0; x1 = nx1;
  }

  float xv[4][4], s1[4] = {0.f, 0.f, 0.f, 0.f}, s2[4] = {0.f, 0.f, 0.f, 0.f};
#pragma unroll
  for (int nt = 0; nt < 4; ++nt) {
    float bb = b3[nw * 64 + nt * 16 + lr];
#pragma unroll
    for (int r = 0; r < 4; ++r) {
      float v = leaky(acc[nt][r] + bb);
      xv[nt][r] = v;
      s1[r] += v;
      s2[r] = fmaf(v, v, s2[r]);
    }
  }
#pragma unroll
  for (int off = 1; off < 16; off <<= 1) {
#pragma unroll
    for (int r = 0; r < 4; ++r) {
      s1[r] += __shfl_xor(s1[r], off);
      s2[r] += __shfl_xor(s2[r], off);
    }
  }
  if (lr == 0) {
#pragma unroll
    for (int r = 0; r < 4; ++r) {
      red[nw][0][lq * 4 + r] = s1[r];
      red[nw][1][lq * 4 + r] = s2[r];
    }
  }
  __syncthreads();
#pragma unroll
  for (int nt = 0; nt < 4; ++nt) {
    int col = nw * 64 + nt * 16 + lr;
    float gg = g3[col], bt = beta3[col];
#pragma unroll
    for (int r = 0; r < 4; ++r) {
      int row = lq * 4 + r;
      float S1 = red[0][0][row] + red[1][0][row];
      float S2 = red[0][1][row] + red[1][1][row];
      float mu = S1 * (1.f / D);
      float var = S2 * (1.f / D) - mu * mu;
      float inv = rsqrtf(var + EPS);
      hbuf[row][col] = f2bf((xv[nt][r] - mu) * inv * gg + bt);
    }
  }
  __syncthreads();

  f32x4 acc2[4];
#pragma unroll
  for (int nt = 0; nt < 4; ++nt) acc2[nt] = (f32x4){0.f, 0.f, 0.f, 0.f};
#pragma unroll
  for (int kc = 0; kc < 4; ++kc) {
    short8 a2 = *(const short8*)&hbuf[lr][kc * 32 + lq * 8];
#pragma unroll
    for (int nt = 0; nt < 4; ++nt) {
      int ncol = nw * 64 + nt * 16 + lr;
      short8 b2 = *(const short8*)(W4T + (size_t)ncol * 128 + kc * 32 + lq * 8);
      acc2[nt] = __builtin_amdgcn_mfma_f32_16x16x32_bf16(a2, b2, acc2[nt], 0, 0, 0);
    }
  }

#pragma unroll
  for (int r = 0; r < 4; ++r) { s1[r] = 0.f; s2[r] = 0.f; }
#pragma unroll
  for (int nt = 0; nt < 4; ++nt) {
    float bb = b4[nw * 64 + nt * 16 + lr];
#pragma unroll
    for (int r = 0; r < 4; ++r) {
      float v = leaky(acc2[nt][r] + bb);
      xv[nt][r] = v;
      s1[r] += v;
      s2[r] = fmaf(v, v, s2[r]);
    }
  }
#pragma unroll
  for (int off = 1; off < 16; off <<= 1) {
#pragma unroll
    for (int r = 0; r < 4; ++r) {
      s1[r] += __shfl_xor(s1[r], off);
      s2[r] += __shfl_xor(s2[r], off);
    }
  }
  __syncthreads();
  if (lr == 0) {
#pragma unroll
    for (int r = 0; r < 4; ++r) {
      red[nw][0][lq * 4 + r] = s1[r];
      red[nw][1][lq * 4 + r] = s2[r];
    }
  }
  __syncthreads();
#pragma unroll
  for (int nt = 0; nt < 4; ++nt) {
    int col = nw * 64 + nt * 16 + lr;
    float gg = g4[col], bt = beta4[col];
#pragma unroll
    for (int r = 0; r < 4; ++r) {
      int row = lq * 4 + r;
      float S1 = red[0][0][row] + red[1][0][row];
      float S2 = red[0][1][row] + red[1][1][row];
      float mu = S1 * (1.f / D);
      float var = S2 * (1.f / D) - mu * mu;
      float inv = rsqrtf(var + EPS);
      out[(size_t)(gb + row) * D + col] = (xv[nt][r] - mu) * inv * gg + bt;
    }
  }
}

extern "C" void kernel_launch(void* const* d_in, const int* in_sizes, int n_in,
                              void* d_out, int out_size, void* d_ws, size_t ws_size,
                              hipStream_t stream) {
  (void)in_sizes; (void)n_in; (void)out_size; (void)ws_size;
  const float* feat  = (const float*)d_in[0];
  const int*   batch = (const int*)d_in[1];
  const float* W1    = (const float*)d_in[2];
  const float* b1    = (const float*)d_in[3];
  const float* g1    = (const float*)d_in[4];
  const float* beta1 = (const float*)d_in[5];
  const float* W2    = (const float*)d_in[6];
  const float* b2    = (const float*)d_in[7];
  const float* W3    = (const float*)d_in[8];
  const float* b3    = (const float*)d_in[9];
  const float* g3    = (const float*)d_in[10];
  const float* beta3 = (const float*)d_in[11];
  const float* W4    = (const float*)d_in[12];
  const float* b4    = (const float*)d_in[13];
  const float* g4    = (const float*)d_in[14];
  const float* beta4 = (const float*)d_in[15];
  float* out = (float*)d_out;

  char* ws = (char*)d_ws;
  float* att     = (float*)ws;                                  // 8 MB
  float* out_row = (float*)(ws + (size_t)NN * NH * 4);          // 16.8 MB
  char*  p       = ws + (size_t)NN * NH * 4 + (size_t)NG * NH * D * 4;
  int*   offs    = (int*)p;                                     // 16.4 KB
  short* W3T     = (short*)(p + 32768);                         // 256 KB
  short* W4T     = (short*)(p + 32768 + 262144);                // 32 KB

  k0_offs<<<(NG + 256) / 256, 256, 0, stream>>>(batch, offs);
  k0b_prep<<<36, 256, 0, stream>>>(W3, W4, W3T, W4T);
  k1_att<<<NN / 128, 256, 0, stream>>>(feat, W1, b1, g1, beta1, W2, b2, att);
  k2_agg<<<NG / 4, 256, 0, stream>>>(feat, offs, att, out_row);
  k3_mlp<<<NG / 16, 128, 0, stream>>>(out_row, W3T, b3, g3, beta3, W4T, b4, g4,
                                      beta4, out);
}

// Round 6
// 274.672 us; speedup vs baseline: 1.1937x; 1.0121x over previous
//
#include <hip/hip_runtime.h>
#include <math.h>

#define NG 4096
#define NN 262144
#define D 128
#define M1 64
#define NH 8
#define EPS 1e-6f

typedef __attribute__((ext_vector_type(8))) short short8;
typedef __attribute__((ext_vector_type(4))) float f32x4;

__device__ inline float leaky(float x) { return x > 0.f ? x : 0.01f * x; }

// fp32 -> bf16 round-to-nearest-even
__device__ inline short f2bf(float f) {
  union { float f; unsigned u; } v; v.f = f;
  unsigned r = (v.u + 0x7fffu + ((v.u >> 16) & 1u)) >> 16;
  return (short)r;
}
__device__ inline float bf2f(short s) {
  union { unsigned u; float f; } v;
  v.u = ((unsigned)(unsigned short)s) << 16;
  return v.f;
}

// ---------------------------------------------------------------------------
// K0b: one-time prep — transpose W3[1024,128] -> W3T[128,1024] bf16 and
// W4[128,128] -> W4T[128,128] bf16 via LDS 64x64 tiles.
// ---------------------------------------------------------------------------
__global__ __launch_bounds__(256) void k0b_prep(
    const float* __restrict__ W3, const float* __restrict__ W4,
    short* __restrict__ W3T, short* __restrict__ W4T) {
  __shared__ float tile[64][65];
  int b = blockIdx.x, t = threadIdx.x;
  const float* src; short* dst; int kt, nt, tkl;
  if (b < 32) { src = W3; dst = W3T; kt = b >> 1; nt = b & 1; tkl = 1024; }
  else        { src = W4; dst = W4T; kt = (b - 32) >> 1; nt = (b - 32) & 1; tkl = 128; }

#pragma unroll
  for (int i = 0; i < 4; ++i) {
    int id = t + 256 * i;
    int r = id >> 4, c4 = (id & 15) * 4;
    float4 v = *(const float4*)(src + (size_t)(kt * 64 + r) * D + nt * 64 + c4);
    tile[r][c4 + 0] = v.x; tile[r][c4 + 1] = v.y;
    tile[r][c4 + 2] = v.z; tile[r][c4 + 3] = v.w;
  }
  __syncthreads();
  int n = t >> 2, kb = (t & 3) * 16;
  short8 p0, p1;
#pragma unroll
  for (int j = 0; j < 8; ++j) {
    p0[j] = f2bf(tile[kb + j][n]);
    p1[j] = f2bf(tile[kb + 8 + j][n]);
  }
  short* o = dst + (size_t)(nt * 64 + n) * tkl + kt * 64 + kb;
  *(short8*)o = p0;
  *(short8*)(o + 8) = p1;
}

// ---------------------------------------------------------------------------
// K1_FUSED: per 128-node block:
//   h = LN64(leaky(feat@W1+b1)); att = exp(h@W2+b2)          (MFMA, as before)
//   then IN-BLOCK aggregation via MFMA:
//     A = att^T masked per graph [(gi,h)=32 x nodes=128]  (graphs gp..gp+3)
//     B = feat [nodes=128 x d=128]  (reloaded from L2, bf16)
//     C partials atomicAdd -> out_acc[g][h*128+d];  s via LDS reduce+atomic.
// Sorted batch => a block spans g_lo..g_hi (usually 2-4 graphs); loop by 4.
// att never hits HBM; feat read once from HBM (+L2-hot re-read).
// ---------------------------------------------------------------------------
__global__ __launch_bounds__(256) void k1_fused(
    const float* __restrict__ feat, const int* __restrict__ batch,
    const float* __restrict__ W1, const float* __restrict__ b1,
    const float* __restrict__ g1, const float* __restrict__ beta1,
    const float* __restrict__ W2, const float* __restrict__ b2,
    float* __restrict__ out_acc, float* __restrict__ s_sum) {
  __shared__ short W1T[M1][D + 8];     // 17408 B
  __shared__ short W2T[16][M1 + 8];    // 2304 B
  __shared__ short hb[128][72];        // 18432 B; first 2 KB reused as attB
  __shared__ int batchL[128];          // 512 B
  short (*attB)[NH] = (short(*)[NH])&hb[0][0];  // [node][h] bf16, after GEMM2

  int t = threadIdx.x;
  int nb = blockIdx.x * 128;

  // ---- stage W1T (transpose 128x64 -> [j][k] bf16)
#pragma unroll
  for (int i = 0; i < 8; ++i) {
    int idx4 = t + 256 * i;
    int k = idx4 >> 4;
    int j = (idx4 & 15) * 4;
    float4 wv = *(const float4*)(W1 + k * M1 + j);
    W1T[j + 0][k] = f2bf(wv.x);
    W1T[j + 1][k] = f2bf(wv.y);
    W1T[j + 2][k] = f2bf(wv.z);
    W1T[j + 3][k] = f2bf(wv.w);
  }
#pragma unroll
  for (int i = 0; i < 4; ++i) {
    int e = t * 4 + i;
    int hh = e >> 6, j = e & 63;
    W2T[hh][j] = (hh < NH) ? f2bf(W2[j * NH + hh]) : (short)0;
  }
  if (t < 128) batchL[t] = batch[nb + t];
  __syncthreads();

  int w = t >> 6, l = t & 63;
  int lr = l & 15, lq = l >> 4;
  int nbw = nb + w * 32;

  // ---- A fragments: this wave's 32 feat rows, fp32 -> bf16
  short8 afr[2][4];
#pragma unroll
  for (int mt = 0; mt < 2; ++mt) {
    const float* rp = feat + (size_t)(nbw + mt * 16 + lr) * D + lq * 8;
#pragma unroll
    for (int c = 0; c < 4; ++c) {
      float4 x0 = *(const float4*)(rp + c * 32);
      float4 x1 = *(const float4*)(rp + c * 32 + 4);
      short8 a;
      a[0] = f2bf(x0.x); a[1] = f2bf(x0.y); a[2] = f2bf(x0.z); a[3] = f2bf(x0.w);
      a[4] = f2bf(x1.x); a[5] = f2bf(x1.y); a[6] = f2bf(x1.z); a[7] = f2bf(x1.w);
      afr[mt][c] = a;
    }
  }

  // ---- GEMM1: [32 nodes x 64 j], K=128
  f32x4 acc[2][4];
#pragma unroll
  for (int mt = 0; mt < 2; ++mt)
#pragma unroll
    for (int nt = 0; nt < 4; ++nt) acc[mt][nt] = (f32x4){0.f, 0.f, 0.f, 0.f};
#pragma unroll
  for (int c = 0; c < 4; ++c) {
#pragma unroll
    for (int nt = 0; nt < 4; ++nt) {
      short8 bfr = *(const short8*)&W1T[nt * 16 + lr][c * 32 + lq * 8];
      acc[0][nt] = __builtin_amdgcn_mfma_f32_16x16x32_bf16(afr[0][c], bfr, acc[0][nt], 0, 0, 0);
      acc[1][nt] = __builtin_amdgcn_mfma_f32_16x16x32_bf16(afr[1][c], bfr, acc[1][nt], 0, 0, 0);
    }
  }

  // ---- bias + leaky + LN over j (64); h -> LDS bf16
  float b1v[4], g1v[4], btv[4];
#pragma unroll
  for (int nt = 0; nt < 4; ++nt) {
    b1v[nt] = b1[nt * 16 + lr];
    g1v[nt] = g1[nt * 16 + lr];
    btv[nt] = beta1[nt * 16 + lr];
  }
#pragma unroll
  for (int mt = 0; mt < 2; ++mt) {
#pragma unroll
    for (int r = 0; r < 4; ++r) {
      float x[4], s1 = 0.f, s2 = 0.f;
#pragma unroll
      for (int nt = 0; nt < 4; ++nt) {
        float xv = leaky(acc[mt][nt][r] + b1v[nt]);
        x[nt] = xv;
        s1 += xv;
        s2 = fmaf(xv, xv, s2);
      }
#pragma unroll
      for (int off = 1; off < 16; off <<= 1) {
        s1 += __shfl_xor(s1, off);
        s2 += __shfl_xor(s2, off);
      }
      float mu = s1 * (1.f / M1);
      float var = s2 * (1.f / M1) - mu * mu;
      float inv = rsqrtf(var + EPS);
      int node = w * 32 + mt * 16 + lq * 4 + r;
#pragma unroll
      for (int nt = 0; nt < 4; ++nt)
        hb[node][nt * 16 + lr] = f2bf((x[nt] - mu) * inv * g1v[nt] + btv[nt]);
    }
  }
  __syncthreads();

  // ---- GEMM2: [32 nodes x 8 heads], K=64
  f32x4 acc2[2];
  acc2[0] = (f32x4){0.f, 0.f, 0.f, 0.f};
  acc2[1] = (f32x4){0.f, 0.f, 0.f, 0.f};
#pragma unroll
  for (int c2 = 0; c2 < 2; ++c2) {
    short8 bfr2 = *(const short8*)&W2T[lr][c2 * 32 + lq * 8];
#pragma unroll
    for (int mt = 0; mt < 2; ++mt) {
      short8 af2 = *(const short8*)&hb[w * 32 + mt * 16 + lr][c2 * 32 + lq * 8];
      acc2[mt] = __builtin_amdgcn_mfma_f32_16x16x32_bf16(af2, bfr2, acc2[mt], 0, 0, 0);
    }
  }
  __syncthreads();          // all hb reads done; hb space now reusable (attB)

  // ---- att = exp(.) -> attB[node][h] (bf16); C layout: col=lr=h, row=node
  if (lr < NH) {
    float b2v = b2[lr];
#pragma unroll
    for (int mt = 0; mt < 2; ++mt)
#pragma unroll
      for (int r = 0; r < 4; ++r)
        attB[w * 32 + mt * 16 + lq * 4 + r][lr] = f2bf(expf(acc2[mt][r] + b2v));
  }
  __syncthreads();

  int g_lo = batchL[0], g_hi = batchL[127];

  // ---- B-frags for aggregation: feat[k=node][n=d], gp-independent -> hoist.
  // d = w*32 + nt2*16 + lr; node = kc*32 + lq*8 + j. L2-hot reload.
  short8 bfA[4], bfB[4];
#pragma unroll
  for (int kc = 0; kc < 4; ++kc) {
    int dA = w * 32 + lr, dB = w * 32 + 16 + lr;
    short8 ba, bb;
#pragma unroll
    for (int j = 0; j < 8; ++j) {
      const float* fp = feat + (size_t)(nb + kc * 32 + lq * 8 + j) * D;
      ba[j] = f2bf(fp[dA]);
      bb[j] = f2bf(fp[dB]);
    }
    bfA[kc] = ba;
    bfB[kc] = bb;
  }

  for (int gp = g_lo; gp <= g_hi; gp += 4) {
    // ---- s partial sums (waves 0,1): combo=(gi,h), 4 threads x 32 nodes
    if (t < 128) {
      int combo = t >> 2;            // 0..31
      int gi = combo >> 3, h = combo & 7;
      int base = (t & 3) * 32;
      float ssum = 0.f;
#pragma unroll
      for (int i = 0; i < 32; ++i) {
        int node = base + i;
        if (batchL[node] == gp + gi) ssum += bf2f(attB[node][h]);
      }
      ssum += __shfl_xor(ssum, 1);
      ssum += __shfl_xor(ssum, 2);
      if ((t & 3) == 0 && gp + gi <= g_hi)
        atomicAdd(s_sum + (gp + gi) * NH + h, ssum);
    }

    // ---- aggregation MFMA: A[m=(gi,h)][k=node] masked; M=32 (2 tiles)
    f32x4 aggc00 = (f32x4){0.f, 0.f, 0.f, 0.f};
    f32x4 aggc01 = (f32x4){0.f, 0.f, 0.f, 0.f};
    f32x4 aggc10 = (f32x4){0.f, 0.f, 0.f, 0.f};
    f32x4 aggc11 = (f32x4){0.f, 0.f, 0.f, 0.f};
    int hA = lr & 7;
    int giA0 = gp + (lr >> 3);       // mt2=0: m=lr -> gi=lr>>3
    int giA1 = gp + 2 + (lr >> 3);   // mt2=1: m=16+lr -> gi=2+(lr>>3)
#pragma unroll
    for (int kc = 0; kc < 4; ++kc) {
      short8 a0, a1;
#pragma unroll
      for (int j = 0; j < 8; ++j) {
        int node = kc * 32 + lq * 8 + j;
        int bg = batchL[node];
        short av = attB[node][hA];
        a0[j] = (bg == giA0) ? av : (short)0;
        a1[j] = (bg == giA1) ? av : (short)0;
      }
      aggc00 = __builtin_amdgcn_mfma_f32_16x16x32_bf16(a0, bfA[kc], aggc00, 0, 0, 0);
      aggc01 = __builtin_amdgcn_mfma_f32_16x16x32_bf16(a0, bfB[kc], aggc01, 0, 0, 0);
      aggc10 = __builtin_amdgcn_mfma_f32_16x16x32_bf16(a1, bfA[kc], aggc10, 0, 0, 0);
      aggc11 = __builtin_amdgcn_mfma_f32_16x16x32_bf16(a1, bfB[kc], aggc11, 0, 0, 0);
    }

    // ---- atomic accumulate: C row m=mt2*16+lq*4+r -> gi=mt2*2+(lq>>1),
    // h=(lq&1)*4+r; col n -> d = w*32 + nt2*16 + lr
    int giC0 = gp + (lq >> 1);
    int giC1 = gp + 2 + (lq >> 1);
    int dA = w * 32 + lr, dB = w * 32 + 16 + lr;
    if (giC0 <= g_hi) {
      float* p0 = out_acc + (size_t)giC0 * (NH * D) + ((lq & 1) * 4) * D;
#pragma unroll
      for (int r = 0; r < 4; ++r) {
        atomicAdd(p0 + r * D + dA, aggc00[r]);
        atomicAdd(p0 + r * D + dB, aggc01[r]);
      }
    }
    if (giC1 <= g_hi) {
      float* p1 = out_acc + (size_t)giC1 * (NH * D) + ((lq & 1) * 4) * D;
#pragma unroll
      for (int r = 0; r < 4; ++r) {
        atomicAdd(p1 + r * D + dA, aggc10[r]);
        atomicAdd(p1 + r * D + dB, aggc11[r]);
      }
    }
  }
}

// ---------------------------------------------------------------------------
// K3 (MFMA bf16): o = LN(leaky((out_acc/s)@W3+b3)); o = LN(leaky(o@W4+b4))
// Normalization fused into the A-frag build: h = kc>>2 is COMPILE-TIME under
// full unroll, so invs[8] stays in registers (runtime indexing would demote
// to LDS — round-4 lesson).
// ---------------------------------------------------------------------------
__global__ __launch_bounds__(128) void k3_mlp(
    const float* __restrict__ X, const float* __restrict__ s_sum,
    const short* __restrict__ W3T,
    const float* __restrict__ b3, const float* __restrict__ g3,
    const float* __restrict__ beta3, const short* __restrict__ W4T,
    const float* __restrict__ b4, const float* __restrict__ g4,
    const float* __restrict__ beta4, float* __restrict__ out) {
  __shared__ short hbuf[16][136];
  __shared__ float red[2][2][16];

  int t = threadIdx.x;
  int nw = t >> 6, l = t & 63;
  int lr = l & 15, lq = l >> 4;
  int gb = blockIdx.x * 16;

  // per-lane softmax-denominator inverses for row g = gb+lr
  float invs[8];
#pragma unroll
  for (int h = 0; h < 8; ++h) {
    float sv = s_sum[(gb + lr) * NH + h];
    invs[h] = sv > 0.f ? 1.f / sv : 0.f;
  }

  const float* xrow = X + (size_t)(gb + lr) * (NH * D) + lq * 8;
  f32x4 acc[4];
#pragma unroll
  for (int nt = 0; nt < 4; ++nt) acc[nt] = (f32x4){0.f, 0.f, 0.f, 0.f};

#pragma unroll
  for (int kc = 0; kc < 32; ++kc) {
    float4 x0 = *(const float4*)(xrow + kc * 32);
    float4 x1 = *(const float4*)(xrow + kc * 32 + 4);
    float inv = invs[kc >> 2];       // compile-time index after unroll
    short8 a;
    a[0] = f2bf(x0.x * inv); a[1] = f2bf(x0.y * inv);
    a[2] = f2bf(x0.z * inv); a[3] = f2bf(x0.w * inv);
    a[4] = f2bf(x1.x * inv); a[5] = f2bf(x1.y * inv);
    a[6] = f2bf(x1.z * inv); a[7] = f2bf(x1.w * inv);
#pragma unroll
    for (int nt = 0; nt < 4; ++nt) {
      int ncol = nw * 64 + nt * 16 + lr;
      short8 b = *(const short8*)(W3T + (size_t)ncol * 1024 + kc * 32 + lq * 8);
      acc[nt] = __builtin_amdgcn_mfma_f32_16x16x32_bf16(a, b, acc[nt], 0, 0, 0);
    }
  }

  float xv[4][4], s1[4] = {0.f, 0.f, 0.f, 0.f}, s2[4] = {0.f, 0.f, 0.f, 0.f};
#pragma unroll
  for (int nt = 0; nt < 4; ++nt) {
    float bb = b3[nw * 64 + nt * 16 + lr];
#pragma unroll
    for (int r = 0; r < 4; ++r) {
      float v = leaky(acc[nt][r] + bb);
      xv[nt][r] = v;
      s1[r] += v;
      s2[r] = fmaf(v, v, s2[r]);
    }
  }
#pragma unroll
  for (int off = 1; off < 16; off <<= 1) {
#pragma unroll
    for (int r = 0; r < 4; ++r) {
      s1[r] += __shfl_xor(s1[r], off);
      s2[r] += __shfl_xor(s2[r], off);
    }
  }
  if (lr == 0) {
#pragma unroll
    for (int r = 0; r < 4; ++r) {
      red[nw][0][lq * 4 + r] = s1[r];
      red[nw][1][lq * 4 + r] = s2[r];
    }
  }
  __syncthreads();
#pragma unroll
  for (int nt = 0; nt < 4; ++nt) {
    int col = nw * 64 + nt * 16 + lr;
    float gg = g3[col], bt = beta3[col];
#pragma unroll
    for (int r = 0; r < 4; ++r) {
      int row = lq * 4 + r;
      float S1 = red[0][0][row] + red[1][0][row];
      float S2 = red[0][1][row] + red[1][1][row];
      float mu = S1 * (1.f / D);
      float var = S2 * (1.f / D) - mu * mu;
      float inv = rsqrtf(var + EPS);
      hbuf[row][col] = f2bf((xv[nt][r] - mu) * inv * gg + bt);
    }
  }
  __syncthreads();

  f32x4 acc2[4];
#pragma unroll
  for (int nt = 0; nt < 4; ++nt) acc2[nt] = (f32x4){0.f, 0.f, 0.f, 0.f};
#pragma unroll
  for (int kc = 0; kc < 4; ++kc) {
    short8 a2 = *(const short8*)&hbuf[lr][kc * 32 + lq * 8];
#pragma unroll
    for (int nt = 0; nt < 4; ++nt) {
      int ncol = nw * 64 + nt * 16 + lr;
      short8 b2 = *(const short8*)(W4T + (size_t)ncol * 128 + kc * 32 + lq * 8);
      acc2[nt] = __builtin_amdgcn_mfma_f32_16x16x32_bf16(a2, b2, acc2[nt], 0, 0, 0);
    }
  }

#pragma unroll
  for (int r = 0; r < 4; ++r) { s1[r] = 0.f; s2[r] = 0.f; }
#pragma unroll
  for (int nt = 0; nt < 4; ++nt) {
    float bb = b4[nw * 64 + nt * 16 + lr];
#pragma unroll
    for (int r = 0; r < 4; ++r) {
      float v = leaky(acc2[nt][r] + bb);
      xv[nt][r] = v;
      s1[r] += v;
      s2[r] = fmaf(v, v, s2[r]);
    }
  }
#pragma unroll
  for (int off = 1; off < 16; off <<= 1) {
#pragma unroll
    for (int r = 0; r < 4; ++r) {
      s1[r] += __shfl_xor(s1[r], off);
      s2[r] += __shfl_xor(s2[r], off);
    }
  }
  __syncthreads();
  if (lr == 0) {
#pragma unroll
    for (int r = 0; r < 4; ++r) {
      red[nw][0][lq * 4 + r] = s1[r];
      red[nw][1][lq * 4 + r] = s2[r];
    }
  }
  __syncthreads();
#pragma unroll
  for (int nt = 0; nt < 4; ++nt) {
    int col = nw * 64 + nt * 16 + lr;
    float gg = g4[col], bt = beta4[col];
#pragma unroll
    for (int r = 0; r < 4; ++r) {
      int row = lq * 4 + r;
      float S1 = red[0][0][row] + red[1][0][row];
      float S2 = red[0][1][row] + red[1][1][row];
      float mu = S1 * (1.f / D);
      float var = S2 * (1.f / D) - mu * mu;
      float inv = rsqrtf(var + EPS);
      out[(size_t)(gb + row) * D + col] = (xv[nt][r] - mu) * inv * gg + bt;
    }
  }
}

extern "C" void kernel_launch(void* const* d_in, const int* in_sizes, int n_in,
                              void* d_out, int out_size, void* d_ws, size_t ws_size,
                              hipStream_t stream) {
  (void)in_sizes; (void)n_in; (void)out_size; (void)ws_size;
  const float* feat  = (const float*)d_in[0];
  const int*   batch = (const int*)d_in[1];
  const float* W1    = (const float*)d_in[2];
  const float* b1    = (const float*)d_in[3];
  const float* g1    = (const float*)d_in[4];
  const float* beta1 = (const float*)d_in[5];
  const float* W2    = (const float*)d_in[6];
  const float* b2    = (const float*)d_in[7];
  const float* W3    = (const float*)d_in[8];
  const float* b3    = (const float*)d_in[9];
  const float* g3    = (const float*)d_in[10];
  const float* beta3 = (const float*)d_in[11];
  const float* W4    = (const float*)d_in[12];
  const float* b4    = (const float*)d_in[13];
  const float* g4    = (const float*)d_in[14];
  const float* beta4 = (const float*)d_in[15];
  float* out = (float*)d_out;

  char* ws = (char*)d_ws;
  float* out_acc = (float*)ws;                            // NG*1024 f32 = 16 MB
  float* s_sum   = (float*)(ws + (size_t)NG * NH * D * 4);  // NG*8 f32 = 128 KB
  char*  p       = ws + (size_t)NG * NH * D * 4 + (size_t)NG * NH * 4;
  short* W3T     = (short*)p;                             // 256 KB
  short* W4T     = (short*)(p + 262144);                  // 32 KB

  // zero accumulators (out_acc + s_sum are contiguous)
  hipMemsetAsync(out_acc, 0, (size_t)NG * NH * D * 4 + (size_t)NG * NH * 4,
                 stream);
  k0b_prep<<<36, 256, 0, stream>>>(W3, W4, W3T, W4T);
  k1_fused<<<NN / 128, 256, 0, stream>>>(feat, batch, W1, b1, g1, beta1, W2, b2,
                                         out_acc, s_sum);
  k3_mlp<<<NG / 16, 128, 0, stream>>>(out_acc, s_sum, W3T, b3, g3, beta3, W4T,
                                      b4, g4, beta4, out);
}

// Round 7
// 260.110 us; speedup vs baseline: 1.2606x; 1.0560x over previous
//
#include <hip/hip_runtime.h>
#include <math.h>

#define NG 4096
#define NN 262144
#define D 128
#define M1 64
#define NH 8
#define EPS 1e-6f

typedef __attribute__((ext_vector_type(8))) short short8;
typedef __attribute__((ext_vector_type(8))) unsigned char uchar8;
typedef __attribute__((ext_vector_type(4))) float f32x4;

__device__ inline float leaky(float x) { return x > 0.f ? x : 0.01f * x; }

// fp32 -> bf16 round-to-nearest-even
__device__ inline short f2bf(float f) {
  union { float f; unsigned u; } v; v.f = f;
  unsigned r = (v.u + 0x7fffu + ((v.u >> 16) & 1u)) >> 16;
  return (short)r;
}
__device__ inline float bf2f(short s) {
  union { unsigned u; float f; } v;
  v.u = ((unsigned)(unsigned short)s) << 16;
  return v.f;
}

// ---------------------------------------------------------------------------
// K0b: one-time prep — transpose W3[1024,128] -> W3T[128,1024] bf16 and
// W4[128,128] -> W4T[128,128] bf16 via LDS 64x64 tiles.
// ---------------------------------------------------------------------------
__global__ __launch_bounds__(256) void k0b_prep(
    const float* __restrict__ W3, const float* __restrict__ W4,
    short* __restrict__ W3T, short* __restrict__ W4T) {
  __shared__ float tile[64][65];
  int b = blockIdx.x, t = threadIdx.x;
  const float* src; short* dst; int kt, nt, tkl;
  if (b < 32) { src = W3; dst = W3T; kt = b >> 1; nt = b & 1; tkl = 1024; }
  else        { src = W4; dst = W4T; kt = (b - 32) >> 1; nt = (b - 32) & 1; tkl = 128; }

#pragma unroll
  for (int i = 0; i < 4; ++i) {
    int id = t + 256 * i;
    int r = id >> 4, c4 = (id & 15) * 4;
    float4 v = *(const float4*)(src + (size_t)(kt * 64 + r) * D + nt * 64 + c4);
    tile[r][c4 + 0] = v.x; tile[r][c4 + 1] = v.y;
    tile[r][c4 + 2] = v.z; tile[r][c4 + 3] = v.w;
  }
  __syncthreads();
  int n = t >> 2, kb = (t & 3) * 16;
  short8 p0, p1;
#pragma unroll
  for (int j = 0; j < 8; ++j) {
    p0[j] = f2bf(tile[kb + j][n]);
    p1[j] = f2bf(tile[kb + 8 + j][n]);
  }
  short* o = dst + (size_t)(nt * 64 + n) * tkl + kt * 64 + kb;
  *(short8*)o = p0;
  *(short8*)(o + 8) = p1;
}

// ---------------------------------------------------------------------------
// K1_FUSED v2: per 128-node block:
//   h = LN64(leaky(feat@W1+b1)); att = exp(h@W2+b2)           (MFMA)
//   in-block aggregation MFMA: A = att^T masked [(gi,h)=32 x node=128],
//   B = feat [node x d] (L2-hot reload), atomics -> out_acc / s_sum.
// Round-6 fix: attB stored [h][node] stride 136 (rows 4 banks apart) so the
// A-build is 1 ds_read_b128 + 1 ds_read_b64 per kc (was 64 conflicted u16
// reads); s computed from registers via shfl at exp time (LDS s-loop gone).
// ---------------------------------------------------------------------------
__global__ __launch_bounds__(256) void k1_fused(
    const float* __restrict__ feat, const int* __restrict__ batch,
    const float* __restrict__ W1, const float* __restrict__ b1,
    const float* __restrict__ g1, const float* __restrict__ beta1,
    const float* __restrict__ W2, const float* __restrict__ b2,
    float* __restrict__ out_acc, float* __restrict__ s_sum) {
  __shared__ short W1T[M1][D + 8];     // 17408 B
  __shared__ short W2T[16][M1 + 8];    // 2304 B
  __shared__ short hb[128][72];        // 18432 B; reused as attB after GEMM2
  __shared__ int batchL[128];          // 512 B
  __shared__ unsigned char giL[128];   // 128 B
  short (*attB)[136] = (short(*)[136])&hb[0][0];  // [h][node], pad->4-bank skew

  int t = threadIdx.x;
  int nb = blockIdx.x * 128;

  // ---- stage W1T (transpose 128x64 -> [j][k] bf16)
#pragma unroll
  for (int i = 0; i < 8; ++i) {
    int idx4 = t + 256 * i;
    int k = idx4 >> 4;
    int j = (idx4 & 15) * 4;
    float4 wv = *(const float4*)(W1 + k * M1 + j);
    W1T[j + 0][k] = f2bf(wv.x);
    W1T[j + 1][k] = f2bf(wv.y);
    W1T[j + 2][k] = f2bf(wv.z);
    W1T[j + 3][k] = f2bf(wv.w);
  }
#pragma unroll
  for (int i = 0; i < 4; ++i) {
    int e = t * 4 + i;
    int hh = e >> 6, j = e & 63;
    W2T[hh][j] = (hh < NH) ? f2bf(W2[j * NH + hh]) : (short)0;
  }
  if (t < 128) batchL[t] = batch[nb + t];
  __syncthreads();

  int w = t >> 6, l = t & 63;
  int lr = l & 15, lq = l >> 4;
  int nbw = nb + w * 32;
  int g_lo = batchL[0], g_hi = batchL[127];

  // ---- A fragments: this wave's 32 feat rows, fp32 -> bf16
  short8 afr[2][4];
#pragma unroll
  for (int mt = 0; mt < 2; ++mt) {
    const float* rp = feat + (size_t)(nbw + mt * 16 + lr) * D + lq * 8;
#pragma unroll
    for (int c = 0; c < 4; ++c) {
      float4 x0 = *(const float4*)(rp + c * 32);
      float4 x1 = *(const float4*)(rp + c * 32 + 4);
      short8 a;
      a[0] = f2bf(x0.x); a[1] = f2bf(x0.y); a[2] = f2bf(x0.z); a[3] = f2bf(x0.w);
      a[4] = f2bf(x1.x); a[5] = f2bf(x1.y); a[6] = f2bf(x1.z); a[7] = f2bf(x1.w);
      afr[mt][c] = a;
    }
  }

  // ---- GEMM1: [32 nodes x 64 j], K=128
  f32x4 acc[2][4];
#pragma unroll
  for (int mt = 0; mt < 2; ++mt)
#pragma unroll
    for (int nt = 0; nt < 4; ++nt) acc[mt][nt] = (f32x4){0.f, 0.f, 0.f, 0.f};
#pragma unroll
  for (int c = 0; c < 4; ++c) {
#pragma unroll
    for (int nt = 0; nt < 4; ++nt) {
      short8 bfr = *(const short8*)&W1T[nt * 16 + lr][c * 32 + lq * 8];
      acc[0][nt] = __builtin_amdgcn_mfma_f32_16x16x32_bf16(afr[0][c], bfr, acc[0][nt], 0, 0, 0);
      acc[1][nt] = __builtin_amdgcn_mfma_f32_16x16x32_bf16(afr[1][c], bfr, acc[1][nt], 0, 0, 0);
    }
  }

  // ---- bias + leaky + LN over j (64); h -> LDS bf16
  float b1v[4], g1v[4], btv[4];
#pragma unroll
  for (int nt = 0; nt < 4; ++nt) {
    b1v[nt] = b1[nt * 16 + lr];
    g1v[nt] = g1[nt * 16 + lr];
    btv[nt] = beta1[nt * 16 + lr];
  }
#pragma unroll
  for (int mt = 0; mt < 2; ++mt) {
#pragma unroll
    for (int r = 0; r < 4; ++r) {
      float x[4], s1 = 0.f, s2 = 0.f;
#pragma unroll
      for (int nt = 0; nt < 4; ++nt) {
        float xv = leaky(acc[mt][nt][r] + b1v[nt]);
        x[nt] = xv;
        s1 += xv;
        s2 = fmaf(xv, xv, s2);
      }
#pragma unroll
      for (int off = 1; off < 16; off <<= 1) {
        s1 += __shfl_xor(s1, off);
        s2 += __shfl_xor(s2, off);
      }
      float mu = s1 * (1.f / M1);
      float var = s2 * (1.f / M1) - mu * mu;
      float inv = rsqrtf(var + EPS);
      int node = w * 32 + mt * 16 + lq * 4 + r;
#pragma unroll
      for (int nt = 0; nt < 4; ++nt)
        hb[node][nt * 16 + lr] = f2bf((x[nt] - mu) * inv * g1v[nt] + btv[nt]);
    }
  }
  __syncthreads();

  // ---- GEMM2: [32 nodes x 8 heads], K=64
  f32x4 acc2[2];
  acc2[0] = (f32x4){0.f, 0.f, 0.f, 0.f};
  acc2[1] = (f32x4){0.f, 0.f, 0.f, 0.f};
#pragma unroll
  for (int c2 = 0; c2 < 2; ++c2) {
    short8 bfr2 = *(const short8*)&W2T[lr][c2 * 32 + lq * 8];
#pragma unroll
    for (int mt = 0; mt < 2; ++mt) {
      short8 af2 = *(const short8*)&hb[w * 32 + mt * 16 + lr][c2 * 32 + lq * 8];
      acc2[mt] = __builtin_amdgcn_mfma_f32_16x16x32_bf16(af2, bfr2, acc2[mt], 0, 0, 0);
    }
  }
  __syncthreads();          // all hb reads done; hb space now attB

  // ---- att = exp(.): store attB[h][node] (bf16), s via register masks+shfl.
  // C layout: col=lr (head), row=node_local = w*32+mt*16+lq*4+r.
  if (lr < NH) {
    float b2v = b2[lr];
    float attv[2][4];
    int bnode[2][4];
#pragma unroll
    for (int mt = 0; mt < 2; ++mt)
#pragma unroll
      for (int r = 0; r < 4; ++r) {
        int node = w * 32 + mt * 16 + lq * 4 + r;
        float av = bf2f(f2bf(expf(acc2[mt][r] + b2v)));  // use rounded value
        attv[mt][r] = av;
        bnode[mt][r] = batchL[node];
        attB[lr][node] = f2bf(av);
      }
    for (int g = g_lo; g <= g_hi; ++g) {
      float ss = 0.f;
#pragma unroll
      for (int mt = 0; mt < 2; ++mt)
#pragma unroll
        for (int r = 0; r < 4; ++r)
          ss += (bnode[mt][r] == g) ? attv[mt][r] : 0.f;
      ss += __shfl_xor(ss, 16);
      ss += __shfl_xor(ss, 32);
      if (lq == 0) atomicAdd(s_sum + g * NH + lr, ss);
    }
  }
  if (t < 128) giL[t] = (unsigned char)(batchL[t] - g_lo);
  __syncthreads();

  // ---- B-frags for aggregation: feat[k=node][n=d], hoisted (L2-hot reload)
  short8 bfA[4], bfB[4];
#pragma unroll
  for (int kc = 0; kc < 4; ++kc) {
    int dA = w * 32 + lr, dB = w * 32 + 16 + lr;
    short8 ba, bb;
#pragma unroll
    for (int j = 0; j < 8; ++j) {
      const float* fp = feat + (size_t)(nb + kc * 32 + lq * 8 + j) * D;
      ba[j] = f2bf(fp[dA]);
      bb[j] = f2bf(fp[dB]);
    }
    bfA[kc] = ba;
    bfB[kc] = bb;
  }

  int hA = lr & 7;
  for (int gp = g_lo; gp <= g_hi; gp += 4) {
    int t0 = (gp - g_lo) + (lr >> 3);   // window-relative graph for M-tile 0
    int t1 = t0 + 2;                     // for M-tile 1
    f32x4 aggc00 = (f32x4){0.f, 0.f, 0.f, 0.f};
    f32x4 aggc01 = (f32x4){0.f, 0.f, 0.f, 0.f};
    f32x4 aggc10 = (f32x4){0.f, 0.f, 0.f, 0.f};
    f32x4 aggc11 = (f32x4){0.f, 0.f, 0.f, 0.f};
#pragma unroll
    for (int kc = 0; kc < 4; ++kc) {
      short8 av = *(const short8*)&attB[hA][kc * 32 + lq * 8];
      uchar8 gv = *(const uchar8*)&giL[kc * 32 + lq * 8];
      short8 a0, a1;
#pragma unroll
      for (int j = 0; j < 8; ++j) {
        short x = av[j];
        a0[j] = (gv[j] == t0) ? x : (short)0;
        a1[j] = (gv[j] == t1) ? x : (short)0;
      }
      aggc00 = __builtin_amdgcn_mfma_f32_16x16x32_bf16(a0, bfA[kc], aggc00, 0, 0, 0);
      aggc01 = __builtin_amdgcn_mfma_f32_16x16x32_bf16(a0, bfB[kc], aggc01, 0, 0, 0);
      aggc10 = __builtin_amdgcn_mfma_f32_16x16x32_bf16(a1, bfA[kc], aggc10, 0, 0, 0);
      aggc11 = __builtin_amdgcn_mfma_f32_16x16x32_bf16(a1, bfB[kc], aggc11, 0, 0, 0);
    }

    // C row m=mt2*16+lq*4+r -> gi=mt2*2+(lq>>1), h=(lq&1)*4+r; col -> d
    int giC0 = gp + (lq >> 1);
    int giC1 = gp + 2 + (lq >> 1);
    int dA = w * 32 + lr, dB = w * 32 + 16 + lr;
    if (giC0 <= g_hi) {
      float* p0 = out_acc + (size_t)giC0 * (NH * D) + ((lq & 1) * 4) * D;
#pragma unroll
      for (int r = 0; r < 4; ++r) {
        atomicAdd(p0 + r * D + dA, aggc00[r]);
        atomicAdd(p0 + r * D + dB, aggc01[r]);
      }
    }
    if (giC1 <= g_hi) {
      float* p1 = out_acc + (size_t)giC1 * (NH * D) + ((lq & 1) * 4) * D;
#pragma unroll
      for (int r = 0; r < 4; ++r) {
        atomicAdd(p1 + r * D + dA, aggc10[r]);
        atomicAdd(p1 + r * D + dB, aggc11[r]);
      }
    }
  }
}

// ---------------------------------------------------------------------------
// K3 (MFMA bf16, unchanged): o = LN(leaky((out_acc/s)@W3+b3));
//                            o = LN(leaky(o@W4+b4))
// ---------------------------------------------------------------------------
__global__ __launch_bounds__(128) void k3_mlp(
    const float* __restrict__ X, const float* __restrict__ s_sum,
    const short* __restrict__ W3T,
    const float* __restrict__ b3, const float* __restrict__ g3,
    const float* __restrict__ beta3, const short* __restrict__ W4T,
    const float* __restrict__ b4, const float* __restrict__ g4,
    const float* __restrict__ beta4, float* __restrict__ out) {
  __shared__ short hbuf[16][136];
  __shared__ float red[2][2][16];

  int t = threadIdx.x;
  int nw = t >> 6, l = t & 63;
  int lr = l & 15, lq = l >> 4;
  int gb = blockIdx.x * 16;

  float invs[8];
#pragma unroll
  for (int h = 0; h < 8; ++h) {
    float sv = s_sum[(gb + lr) * NH + h];
    invs[h] = sv > 0.f ? 1.f / sv : 0.f;
  }

  const float* xrow = X + (size_t)(gb + lr) * (NH * D) + lq * 8;
  f32x4 acc[4];
#pragma unroll
  for (int nt = 0; nt < 4; ++nt) acc[nt] = (f32x4){0.f, 0.f, 0.f, 0.f};

#pragma unroll
  for (int kc = 0; kc < 32; ++kc) {
    float4 x0 = *(const float4*)(xrow + kc * 32);
    float4 x1 = *(const float4*)(xrow + kc * 32 + 4);
    float inv = invs[kc >> 2];       // compile-time index after unroll
    short8 a;
    a[0] = f2bf(x0.x * inv); a[1] = f2bf(x0.y * inv);
    a[2] = f2bf(x0.z * inv); a[3] = f2bf(x0.w * inv);
    a[4] = f2bf(x1.x * inv); a[5] = f2bf(x1.y * inv);
    a[6] = f2bf(x1.z * inv); a[7] = f2bf(x1.w * inv);
#pragma unroll
    for (int nt = 0; nt < 4; ++nt) {
      int ncol = nw * 64 + nt * 16 + lr;
      short8 b = *(const short8*)(W3T + (size_t)ncol * 1024 + kc * 32 + lq * 8);
      acc[nt] = __builtin_amdgcn_mfma_f32_16x16x32_bf16(a, b, acc[nt], 0, 0, 0);
    }
  }

  float xv[4][4], s1[4] = {0.f, 0.f, 0.f, 0.f}, s2[4] = {0.f, 0.f, 0.f, 0.f};
#pragma unroll
  for (int nt = 0; nt < 4; ++nt) {
    float bb = b3[nw * 64 + nt * 16 + lr];
#pragma unroll
    for (int r = 0; r < 4; ++r) {
      float v = leaky(acc[nt][r] + bb);
      xv[nt][r] = v;
      s1[r] += v;
      s2[r] = fmaf(v, v, s2[r]);
    }
  }
#pragma unroll
  for (int off = 1; off < 16; off <<= 1) {
#pragma unroll
    for (int r = 0; r < 4; ++r) {
      s1[r] += __shfl_xor(s1[r], off);
      s2[r] += __shfl_xor(s2[r], off);
    }
  }
  if (lr == 0) {
#pragma unroll
    for (int r = 0; r < 4; ++r) {
      red[nw][0][lq * 4 + r] = s1[r];
      red[nw][1][lq * 4 + r] = s2[r];
    }
  }
  __syncthreads();
#pragma unroll
  for (int nt = 0; nt < 4; ++nt) {
    int col = nw * 64 + nt * 16 + lr;
    float gg = g3[col], bt = beta3[col];
#pragma unroll
    for (int r = 0; r < 4; ++r) {
      int row = lq * 4 + r;
      float S1 = red[0][0][row] + red[1][0][row];
      float S2 = red[0][1][row] + red[1][1][row];
      float mu = S1 * (1.f / D);
      float var = S2 * (1.f / D) - mu * mu;
      float inv = rsqrtf(var + EPS);
      hbuf[row][col] = f2bf((xv[nt][r] - mu) * inv * gg + bt);
    }
  }
  __syncthreads();

  f32x4 acc2[4];
#pragma unroll
  for (int nt = 0; nt < 4; ++nt) acc2[nt] = (f32x4){0.f, 0.f, 0.f, 0.f};
#pragma unroll
  for (int kc = 0; kc < 4; ++kc) {
    short8 a2 = *(const short8*)&hbuf[lr][kc * 32 + lq * 8];
#pragma unroll
    for (int nt = 0; nt < 4; ++nt) {
      int ncol = nw * 64 + nt * 16 + lr;
      short8 b2 = *(const short8*)(W4T + (size_t)ncol * 128 + kc * 32 + lq * 8);
      acc2[nt] = __builtin_amdgcn_mfma_f32_16x16x32_bf16(a2, b2, acc2[nt], 0, 0, 0);
    }
  }

#pragma unroll
  for (int r = 0; r < 4; ++r) { s1[r] = 0.f; s2[r] = 0.f; }
#pragma unroll
  for (int nt = 0; nt < 4; ++nt) {
    float bb = b4[nw * 64 + nt * 16 + lr];
#pragma unroll
    for (int r = 0; r < 4; ++r) {
      float v = leaky(acc2[nt][r] + bb);
      xv[nt][r] = v;
      s1[r] += v;
      s2[r] = fmaf(v, v, s2[r]);
    }
  }
#pragma unroll
  for (int off = 1; off < 16; off <<= 1) {
#pragma unroll
    for (int r = 0; r < 4; ++r) {
      s1[r] += __shfl_xor(s1[r], off);
      s2[r] += __shfl_xor(s2[r], off);
    }
  }
  __syncthreads();
  if (lr == 0) {
#pragma unroll
    for (int r = 0; r < 4; ++r) {
      red[nw][0][lq * 4 + r] = s1[r];
      red[nw][1][lq * 4 + r] = s2[r];
    }
  }
  __syncthreads();
#pragma unroll
  for (int nt = 0; nt < 4; ++nt) {
    int col = nw * 64 + nt * 16 + lr;
    float gg = g4[col], bt = beta4[col];
#pragma unroll
    for (int r = 0; r < 4; ++r) {
      int row = lq * 4 + r;
      float S1 = red[0][0][row] + red[1][0][row];
      float S2 = red[0][1][row] + red[1][1][row];
      float mu = S1 * (1.f / D);
      float var = S2 * (1.f / D) - mu * mu;
      float inv = rsqrtf(var + EPS);
      out[(size_t)(gb + row) * D + col] = (xv[nt][r] - mu) * inv * gg + bt;
    }
  }
}

extern "C" void kernel_launch(void* const* d_in, const int* in_sizes, int n_in,
                              void* d_out, int out_size, void* d_ws, size_t ws_size,
                              hipStream_t stream) {
  (void)in_sizes; (void)n_in; (void)out_size; (void)ws_size;
  const float* feat  = (const float*)d_in[0];
  const int*   batch = (const int*)d_in[1];
  const float* W1    = (const float*)d_in[2];
  const float* b1    = (const float*)d_in[3];
  const float* g1    = (const float*)d_in[4];
  const float* beta1 = (const float*)d_in[5];
  const float* W2    = (const float*)d_in[6];
  const float* b2    = (const float*)d_in[7];
  const float* W3    = (const float*)d_in[8];
  const float* b3    = (const float*)d_in[9];
  const float* g3    = (const float*)d_in[10];
  const float* beta3 = (const float*)d_in[11];
  const float* W4    = (const float*)d_in[12];
  const float* b4    = (const float*)d_in[13];
  const float* g4    = (const float*)d_in[14];
  const float* beta4 = (const float*)d_in[15];
  float* out = (float*)d_out;

  char* ws = (char*)d_ws;
  float* out_acc = (float*)ws;                              // NG*1024 f32
  float* s_sum   = (float*)(ws + (size_t)NG * NH * D * 4);  // NG*8 f32
  char*  p       = ws + (size_t)NG * NH * D * 4 + (size_t)NG * NH * 4;
  short* W3T     = (short*)p;                               // 256 KB
  short* W4T     = (short*)(p + 262144);                    // 32 KB

  hipMemsetAsync(out_acc, 0, (size_t)NG * NH * D * 4 + (size_t)NG * NH * 4,
                 stream);
  k0b_prep<<<36, 256, 0, stream>>>(W3, W4, W3T, W4T);
  k1_fused<<<NN / 128, 256, 0, stream>>>(feat, batch, W1, b1, g1, beta1, W2, b2,
                                         out_acc, s_sum);
  k3_mlp<<<NG / 16, 128, 0, stream>>>(out_acc, s_sum, W3T, b3, g3, beta3, W4T,
                                      b4, g4, beta4, out);
}